// Round 6
// baseline (243.448 us; speedup 1.0000x reference)
//
#include <hip/hip_runtime.h>

#define B_ 16
#define N_ 16384
#define S_ 4096
#define K_ 16
#define TS 32
#define DOUT 128

typedef __bf16 bf16;
typedef __attribute__((ext_vector_type(8))) __bf16 bf16x8;
typedef __attribute__((ext_vector_type(4))) float f32x4;

__device__ __forceinline__ unsigned pack2(float a, float b) {
  unsigned short ua = __builtin_bit_cast(unsigned short, (bf16)a);
  unsigned short ub = __builtin_bit_cast(unsigned short, (bf16)b);
  return (unsigned)ua | ((unsigned)ub << 16);
}

template <int NCH>
__device__ __forceinline__ void ln_leaky(const float* h, const float* g, const float* e, float* o) {
  float m = 0.f;
#pragma unroll
  for (int j = 0; j < NCH; ++j) m += h[j];
  m *= (1.0f / NCH);
  float v = 0.f;
#pragma unroll
  for (int j = 0; j < NCH; ++j) { float d = h[j] - m; v += d * d; }
  v *= (1.0f / NCH);
  float inv = rsqrtf(v + 1e-5f);
#pragma unroll
  for (int j = 0; j < NCH; ++j) {
    float t = (h[j] - m) * inv * g[j] + e[j];
    o[j] = t < 0.f ? 0.2f * t : t;
  }
}

__global__ void k_fill(float* out, float v) {
  out[blockIdx.x * 256 + threadIdx.x] = v;
}

// Fused prep: blocks [0,1024) transpose points [B,64,N] f32 -> ptT [B,N,64] bf16
// with XCD-affine batch mapping; blocks [1024,1296) build wlF.
__global__ __launch_bounds__(256) void k_prep(const float* __restrict__ pts,
                                              bf16* __restrict__ pt,
                                              const float* __restrict__ wl,
                                              bf16* __restrict__ wlF) {
  int bi = blockIdx.x;
  if (bi < 1024) {
    int xcd = bi & 7;
    int li = bi >> 3;                  // 0..127
    int b = xcd * 2 + (li >> 6);       // batch: XCD x -> {2x, 2x+1}
    int n0 = (li & 63) * 256;
    int tc = threadIdx.x & 7;
    int tn = threadIdx.x >> 3;
    const float* src = pts + (size_t)b * 64 * N_ + (size_t)(tc * 8) * N_ + n0 + tn * 8;
    float4 row[8][2];
#pragma unroll
    for (int i = 0; i < 8; ++i) {
      row[i][0] = *(const float4*)(src + (size_t)i * N_);
      row[i][1] = *(const float4*)(src + (size_t)i * N_ + 4);
    }
    bf16* dst = pt + ((size_t)b * N_ + n0 + tn * 8) * 64 + tc * 8;
#pragma unroll
    for (int j = 0; j < 8; ++j) {
      float v[8];
#pragma unroll
      for (int i = 0; i < 8; ++i) {
        float4 q = row[i][j >> 2];
        v[i] = ((j & 3) == 0) ? q.x : ((j & 3) == 1) ? q.y : ((j & 3) == 2) ? q.z : q.w;
      }
      *(uint4*)(dst + (size_t)j * 64) = make_uint4(
          pack2(v[0], v[1]), pack2(v[2], v[3]), pack2(v[4], v[5]), pack2(v[6], v[7]));
    }
  } else {
    int blk = bi - 1024;               // t*34 + kkg
    int kkg = blk % 34;
    int t = blk / 34;
    int tid = threadIdx.x;
    int L = tid >> 2, jp = (tid & 3) * 2;
    int k = kkg * 32 + ((L >> 4) << 3) + jp;
    int n = t * 16 + (L & 15);
    float v0 = (k < 1072) ? wl[(size_t)k * 128 + n] : 0.f;
    float v1 = (k + 1 < 1072) ? wl[(size_t)(k + 1) * 128 + n] : 0.f;
    ((unsigned*)wlF)[(size_t)blk * 256 + tid] = pack2(v0, v1);
  }
}

// 512 threads/block, TS=32: LDS 35.8KB -> 4 blocks/CU x 8 waves = 32 waves/CU
// (100% occupancy cap vs 50% at 256 threads). Per-thread work halves; one
// nnidx load serves both weightnet and gather.
__global__ __launch_bounds__(512, 8) void k_main(
    const float* __restrict__ xyz, const float* __restrict__ nxyz,
    const int* __restrict__ nnidx,
    const bf16* __restrict__ ptT, const bf16* __restrict__ wlF,
    const float* __restrict__ w0p, const float* __restrict__ b0p,
    const float* __restrict__ g0p, const float* __restrict__ be0p,
    const float* __restrict__ w1p, const float* __restrict__ b1p,
    const float* __restrict__ g1p, const float* __restrict__ be1p,
    const float* __restrict__ w2p, const float* __restrict__ b2p,
    const float* __restrict__ g2p, const float* __restrict__ be2p,
    const float* __restrict__ blp, const float* __restrict__ glp,
    const float* __restrict__ belp, float* __restrict__ out) {
  __shared__ __align__(16) bf16 w_sT[32 * 264];   // [s][m*16+k], s-stride 264 (pad 8)
  __shared__ __align__(16) bf16 feat2[32 * 144];  // [s][c*16+k], s-stride 144 (pad 16)
  __shared__ __align__(16) bf16 aggA[32 * 136];   // [s][c*16+m], s-stride 136 (pad 8)
  __shared__ float nx[3][TS];
  __shared__ float ln_m[TS], ln_i[TS];

  const int tid = threadIdx.x;
  // XCD-affinity: XCD x owns batches {2x, 2x+1} (bijective remap).
  const unsigned Lwg = blockIdx.y * 128u + blockIdx.x;
  const int xcd = (int)(Lwg & 7u);
  const int li = (int)(Lwg >> 3);          // 0..255 within XCD
  const int b = xcd * 2 + (li >> 7);       // batch
  const int s0 = (li & 127) * TS;          // s-tile origin
  const size_t ibase = ((size_t)b * S_ + s0) * K_;

  if (tid < 96) {
    int c = tid >> 5, j = tid & 31;
    nx[c][j] = nxyz[((size_t)b * 3 + c) * S_ + s0 + j];
  }
  // one point per thread: p = tid; s = tid>>4, k = tid&15
  const int ig = nnidx[ibase + tid];
  const int ps = tid >> 4;
  const int pk = tid & 15;

  const bf16* ptB = ptT + (size_t)b * N_ * 64;
  // issue chunk-0 gather now; weightnet VALU covers the latency
  uint4 pf = *(const uint4*)(ptB + (size_t)ig * 64);
  __syncthreads();  // nx ready

  // ---- WeightNet: one point (ps, pk) per thread ----
  float xa[3];
  {
#pragma unroll
    for (int c = 0; c < 3; ++c)
      xa[c] = xyz[((size_t)b * 3 + c) * N_ + ig] - nx[c][ps];
    float ya[8];
    {
      float h0[8];
#pragma unroll
      for (int j = 0; j < 8; ++j)
        h0[j] = b0p[j] + xa[0] * w0p[j] + xa[1] * w0p[8 + j] + xa[2] * w0p[16 + j];
      ln_leaky<8>(h0, g0p, be0p, ya);
    }
    {
      float h0[8];
#pragma unroll
      for (int j = 0; j < 8; ++j) h0[j] = b1p[j];
#pragma unroll
      for (int i = 0; i < 8; ++i) {
#pragma unroll
        for (int j = 0; j < 8; ++j) h0[j] += ya[i] * w1p[i * 8 + j];
      }
      ln_leaky<8>(h0, g1p, be1p, ya);
    }
    {
      float h0[16];
#pragma unroll
      for (int j = 0; j < 16; ++j) h0[j] = b2p[j];
#pragma unroll
      for (int i = 0; i < 8; ++i) {
#pragma unroll
        for (int j = 0; j < 16; ++j) h0[j] += ya[i] * w2p[i * 16 + j];
      }
      float z0[16];
      ln_leaky<16>(h0, g2p, be2p, z0);
      bf16* wp = w_sT + ps * 264 + pk;
#pragma unroll
      for (int m = 0; m < 16; ++m) wp[m * 16] = (bf16)z0[m];
    }
  }

  // ---- MFMA wave geometry (8 waves) ----
  const int lane = tid & 63;
  const int wv = tid >> 6;      // 0..7
  const int rt = wv & 1;        // main-GEMM row tile
  const int ct = wv >> 1;       // main-GEMM col tile (0..3): cols {ct*16, 64+ct*16}
  const int l16 = lane & 15;
  const int q = lane >> 4;
  // agg-MFMA lane roles
  const bool adiag = ((((lane >> 5) ^ (lane >> 3)) & 1) == 0);
  const int aoff = ((lane >> 3) & 1) * 144 + (lane & 7) * 16 + (q & 1) * 8;
  const int boff = (lane >> 5) * 264 + l16 * 16 + (q & 1) * 8;
  const int soff = (lane >> 5) * 136 + (q & 1) * 64 + l16;  // + r*16
  f32x4 a0 = {0.f, 0.f, 0.f, 0.f};
  f32x4 a1 = a0;
  const f32x4 zc = a0;

  bf16* fdst = feat2 + ps * 144 + pk;

  for (int ch = 0; ch < 9; ++ch) {
    const int nkk = (ch < 8) ? 4 : 2;
    __syncthreads();  // (A) prev agg done with feat2/w_sT; prev main done with aggA
    // stage feat2[s][c*16+k] for this chunk (1 point per thread)
    if (ch < 8) {
      bf16 t0[8];
      *(uint4*)t0 = pf;
#pragma unroll
      for (int c = 0; c < 8; ++c) fdst[c * 16] = t0[c];
    } else {
      // gxn channels (3 real + 5 zero)
      fdst[0 * 16] = (bf16)xa[0];
      fdst[1 * 16] = (bf16)xa[1];
      fdst[2 * 16] = (bf16)xa[2];
#pragma unroll
      for (int c = 3; c < 8; ++c) fdst[c * 16] = (bf16)0.f;
    }
    __syncthreads();  // (B)
    if (ch < 7) {  // prefetch next chunk's gather
      pf = *(const uint4*)(ptB + (size_t)ig * 64 + (ch + 1) * 8);
    }
    // agg via block-diagonal MFMA: 2 s per MFMA, 2 MFMAs per wave
#pragma unroll
    for (int pp = 0; pp < 2; ++pp) {
      int s2 = wv * 4 + pp * 2;
      uint4 au = *(const uint4*)(feat2 + s2 * 144 + aoff);
      if (!adiag) au = make_uint4(0u, 0u, 0u, 0u);
      bf16x8 af = __builtin_bit_cast(bf16x8, au);
      bf16x8 bw = *(const bf16x8*)(w_sT + s2 * 264 + boff);
      f32x4 d = __builtin_amdgcn_mfma_f32_16x16x32_bf16(af, bw, zc, 0, 0, 0);
      bf16* cp = aggA + s2 * 136 + soff;
#pragma unroll
      for (int r = 0; r < 4; ++r) cp[r * 16] = (bf16)d[r];
    }
    __syncthreads();  // (C)
    // main GEMM: A from aggA (LDS), B from wlF (global, coalesced 1KB/wave).
    // Wave wv: rows rt*16.., col tiles {ct, ct+4} -> cols {ct*16, 64+ct*16}.
    {
      const bf16* arow = aggA + (rt * 16 + l16) * 136 + q * 8;
      const size_t lb = (size_t)lane * 8;
      const size_t kb = (size_t)(ch * 4) * 512;
      const bf16* w0f = wlF + (size_t)ct * 17408 + kb + lb;
      const bf16* w1f = wlF + (size_t)(ct + 4) * 17408 + kb + lb;
      for (int kk = 0; kk < nkk; ++kk) {
        bf16x8 af = *(const bf16x8*)(arow + kk * 32);
        bf16x8 bf0 = *(const bf16x8*)(w0f + kk * 512);
        bf16x8 bf1 = *(const bf16x8*)(w1f + kk * 512);
        a0 = __builtin_amdgcn_mfma_f32_16x16x32_bf16(af, bf0, a0, 0, 0, 0);
        a1 = __builtin_amdgcn_mfma_f32_16x16x32_bf16(af, bf1, a1, 0, 0, 0);
      }
    }
  }

  __syncthreads();
  // ---- epilogue: +bl, LN(128), *gl+bel, leaky, transposed f32 store ----
  float* out_s = (float*)w_sT;  // [32][132]; w_sT dead now (exactly 16896B)
  {
    int row = rt * 16 + q * 4;
    int c0 = ct * 16 + l16;
    int c1 = 64 + c0;
    float bl0 = blp[c0], bl1 = blp[c1];
#pragma unroll
    for (int r = 0; r < 4; ++r) {
      out_s[(row + r) * 132 + c0] = a0[r] + bl0;
      out_s[(row + r) * 132 + c1] = a1[r] + bl1;
    }
  }
  __syncthreads();
  {
    int r = tid >> 4, g = tid & 15;  // 16 threads per row, 8 cols each
    const float* rowp = out_s + r * 132;
    float s1 = 0.f;
#pragma unroll
    for (int i = 0; i < 8; ++i) s1 += rowp[g + 16 * i];
    s1 += __shfl_xor(s1, 1);
    s1 += __shfl_xor(s1, 2);
    s1 += __shfl_xor(s1, 4);
    s1 += __shfl_xor(s1, 8);
    float m = s1 * (1.0f / 128.0f);
    float s2 = 0.f;
#pragma unroll
    for (int i = 0; i < 8; ++i) { float d = rowp[g + 16 * i] - m; s2 += d * d; }
    s2 += __shfl_xor(s2, 1);
    s2 += __shfl_xor(s2, 2);
    s2 += __shfl_xor(s2, 4);
    s2 += __shfl_xor(s2, 8);
    if (g == 0) {
      ln_m[r] = m;
      ln_i[r] = rsqrtf(s2 * (1.0f / 128.0f) + 1e-5f);
    }
  }
  __syncthreads();
  {
    int d = tid >> 2, sh = tid & 3;  // 4 threads per output channel, 8 rows each
    float gld = glp[d], beld = belp[d];
    float vals[8];
#pragma unroll
    for (int j = 0; j < 8; ++j) {
      int r = sh * 8 + j;
      float v = (out_s[r * 132 + d] - ln_m[r]) * ln_i[r] * gld + beld;
      vals[j] = v < 0.f ? 0.2f * v : v;
    }
    float* op = out + ((size_t)b * DOUT + d) * S_ + s0 + sh * 8;
    *(float4*)(op + 0) = make_float4(vals[0], vals[1], vals[2], vals[3]);
    *(float4*)(op + 4) = make_float4(vals[4], vals[5], vals[6], vals[7]);
  }
}

extern "C" void kernel_launch(void* const* d_in, const int* in_sizes, int n_in,
                              void* d_out, int out_size, void* d_ws, size_t ws_size,
                              hipStream_t stream) {
  const float* xyz  = (const float*)d_in[0];
  const float* pts  = (const float*)d_in[1];
  const float* nxyz = (const float*)d_in[2];
  const int* nnidx  = (const int*)d_in[3];
  const float* w0p  = (const float*)d_in[4];
  const float* b0p  = (const float*)d_in[5];
  const float* g0p  = (const float*)d_in[6];
  const float* be0p = (const float*)d_in[7];
  const float* w1p  = (const float*)d_in[8];
  const float* b1p  = (const float*)d_in[9];
  const float* g1p  = (const float*)d_in[10];
  const float* be1p = (const float*)d_in[11];
  const float* w2p  = (const float*)d_in[12];
  const float* b2p  = (const float*)d_in[13];
  const float* g2p  = (const float*)d_in[14];
  const float* be2p = (const float*)d_in[15];
  const float* wlp  = (const float*)d_in[16];
  const float* blp  = (const float*)d_in[17];
  const float* glp  = (const float*)d_in[18];
  const float* belp = (const float*)d_in[19];
  float* out = (float*)d_out;

  const size_t PTT_BYTES = (size_t)B_ * N_ * 64 * 2;       // 33.55 MB
  const size_t WLF_BYTES = (size_t)8 * 34 * 64 * 8 * 2;    // 0.27 MB
  bf16* ptT = (bf16*)d_ws;
  bf16* wlF = (bf16*)((char*)d_ws + PTT_BYTES);

  (void)hipGetLastError();

  if (ws_size < PTT_BYTES + WLF_BYTES) {
    k_fill<<<dim3(8), dim3(256), 0, stream>>>(out, 5000.0f);
    return;
  }

  k_prep<<<dim3(1024 + 8 * 34), dim3(256), 0, stream>>>(pts, ptT, wlp, wlF);
  hipError_t e1 = hipGetLastError();
  k_main<<<dim3(S_ / TS, B_), dim3(512), 0, stream>>>(
      xyz, nxyz, nnidx, ptT, wlF,
      w0p, b0p, g0p, be0p, w1p, b1p, g1p, be1p,
      w2p, b2p, g2p, be2p, blp, glp, belp, out);
  hipError_t e3 = hipGetLastError();

  if (e1 != hipSuccess)
    k_fill<<<dim3(8), dim3(256), 0, stream>>>(out, 2000.0f + (float)(int)e1);
  if (e3 != hipSuccess)
    k_fill<<<dim3(8), dim3(256), 0, stream>>>(out, 4000.0f + (float)(int)e3);
}

// Round 7
// 231.837 us; speedup vs baseline: 1.0501x; 1.0501x over previous
//
#include <hip/hip_runtime.h>

#define B_ 16
#define N_ 16384
#define S_ 4096
#define K_ 16
#define TS 32
#define DOUT 128

typedef __bf16 bf16;
typedef __attribute__((ext_vector_type(8))) __bf16 bf16x8;
typedef __attribute__((ext_vector_type(4))) float f32x4;

__device__ __forceinline__ unsigned pack2(float a, float b) {
  unsigned short ua = __builtin_bit_cast(unsigned short, (bf16)a);
  unsigned short ub = __builtin_bit_cast(unsigned short, (bf16)b);
  return (unsigned)ua | ((unsigned)ub << 16);
}

template <int NCH>
__device__ __forceinline__ void ln_leaky(const float* h, const float* g, const float* e, float* o) {
  float m = 0.f;
#pragma unroll
  for (int j = 0; j < NCH; ++j) m += h[j];
  m *= (1.0f / NCH);
  float v = 0.f;
#pragma unroll
  for (int j = 0; j < NCH; ++j) { float d = h[j] - m; v += d * d; }
  v *= (1.0f / NCH);
  float inv = rsqrtf(v + 1e-5f);
#pragma unroll
  for (int j = 0; j < NCH; ++j) {
    float t = (h[j] - m) * inv * g[j] + e[j];
    o[j] = t < 0.f ? 0.2f * t : t;
  }
}

__global__ void k_fill(float* out, float v) {
  out[blockIdx.x * 256 + threadIdx.x] = v;
}

// Fused prep: blocks [0,1024) transpose points [B,64,N] f32 -> ptT [B,N,64] bf16
// with XCD-affine batch mapping; blocks [1024,1296) build wlF.
// wlF k-order within each 32-wide granule is m-major: position p = m*2 + cl2,
// channel c = kkg*2 + cl2 (matches the packed aggA write layout in k_main).
__global__ __launch_bounds__(256) void k_prep(const float* __restrict__ pts,
                                              bf16* __restrict__ pt,
                                              const float* __restrict__ wl,
                                              bf16* __restrict__ wlF) {
  int bi = blockIdx.x;
  if (bi < 1024) {
    int xcd = bi & 7;
    int li = bi >> 3;                  // 0..127
    int b = xcd * 2 + (li >> 6);       // batch: XCD x -> {2x, 2x+1}
    int n0 = (li & 63) * 256;
    int tc = threadIdx.x & 7;
    int tn = threadIdx.x >> 3;
    const float* src = pts + (size_t)b * 64 * N_ + (size_t)(tc * 8) * N_ + n0 + tn * 8;
    float4 row[8][2];
#pragma unroll
    for (int i = 0; i < 8; ++i) {
      row[i][0] = *(const float4*)(src + (size_t)i * N_);
      row[i][1] = *(const float4*)(src + (size_t)i * N_ + 4);
    }
    bf16* dst = pt + ((size_t)b * N_ + n0 + tn * 8) * 64 + tc * 8;
#pragma unroll
    for (int j = 0; j < 8; ++j) {
      float v[8];
#pragma unroll
      for (int i = 0; i < 8; ++i) {
        float4 q = row[i][j >> 2];
        v[i] = ((j & 3) == 0) ? q.x : ((j & 3) == 1) ? q.y : ((j & 3) == 2) ? q.z : q.w;
      }
      *(uint4*)(dst + (size_t)j * 64) = make_uint4(
          pack2(v[0], v[1]), pack2(v[2], v[3]), pack2(v[4], v[5]), pack2(v[6], v[7]));
    }
  } else {
    int blk = bi - 1024;               // t*34 + kkg
    int kkg = blk % 34;
    int t = blk / 34;
    int tid = threadIdx.x;
    int L = tid >> 2, jp = (tid & 3) * 2;
    int p0 = ((L >> 4) << 3) + jp;     // even position within 32-granule
    int m = p0 >> 1;
    int c0 = kkg * 2;                  // cl2 = 0
    int c1 = c0 + 1;                   // cl2 = 1
    int n = t * 16 + (L & 15);
    float v0 = (c0 < 67) ? wl[(size_t)(c0 * 16 + m) * 128 + n] : 0.f;
    float v1 = (c1 < 67) ? wl[(size_t)(c1 * 16 + m) * 128 + n] : 0.f;
    ((unsigned*)wlF)[(size_t)blk * 256 + tid] = pack2(v0, v1);
  }
}

__global__ __launch_bounds__(256, 4) void k_main(
    const float* __restrict__ xyz, const float* __restrict__ nxyz,
    const int* __restrict__ nnidx,
    const bf16* __restrict__ ptT, const bf16* __restrict__ wlF,
    const float* __restrict__ w0p, const float* __restrict__ b0p,
    const float* __restrict__ g0p, const float* __restrict__ be0p,
    const float* __restrict__ w1p, const float* __restrict__ b1p,
    const float* __restrict__ g1p, const float* __restrict__ be1p,
    const float* __restrict__ w2p, const float* __restrict__ b2p,
    const float* __restrict__ g2p, const float* __restrict__ be2p,
    const float* __restrict__ blp, const float* __restrict__ glp,
    const float* __restrict__ belp, float* __restrict__ out) {
  // LDS (36.1 KB total -> 4 blocks/CU):
  __shared__ __align__(16) bf16 w_sT[32 * 264];   // [s][m*16+k], s-stride 264 (pad 8)
  __shared__ __align__(16) bf16 feat2[32 * 144];  // [s][c*16+k], s-stride 144 (pad 16)
  __shared__ __align__(16) bf16 aggA[32 * 160];   // [s][granule-packed], s-stride 160
  __shared__ float nx[3][TS];
  __shared__ float ln_m[TS], ln_i[TS];

  const int tid = threadIdx.x;
  // XCD-affinity: XCD x owns batches {2x, 2x+1} (bijective remap).
  const unsigned Lwg = blockIdx.y * 128u + blockIdx.x;
  const int xcd = (int)(Lwg & 7u);
  const int li = (int)(Lwg >> 3);          // 0..255 within XCD
  const int b = xcd * 2 + (li >> 7);       // batch
  const int s0 = (li & 127) * TS;          // s-tile origin
  const size_t ibase = ((size_t)b * S_ + s0) * K_;

  if (tid < 96) {
    int c = tid >> 5, j = tid & 31;
    nx[c][j] = nxyz[((size_t)b * 3 + c) * S_ + s0 + j];
  }
  // ONE index pair per thread: points (s = tid>>3, k = 2*(tid&7)) and +1.
  // Serves both WeightNet and the gather staging (paired-k b32 writes).
  const int iw0 = nnidx[ibase + 2 * tid];
  const int iw1 = nnidx[ibase + 2 * tid + 1];
  __syncthreads();

  // ---- WeightNet: points (ws, wk) and (ws, wk+1) ----
  float xa[3], xb[3];
  const int ws = tid >> 3;        // s
  const int wk = (tid & 7) * 2;   // even k
  {
#pragma unroll
    for (int c = 0; c < 3; ++c) {
      float nv = nx[c][ws];
      xa[c] = xyz[((size_t)b * 3 + c) * N_ + iw0] - nv;
      xb[c] = xyz[((size_t)b * 3 + c) * N_ + iw1] - nv;
    }
    float ya[8], yb[8];
    {
      float h0[8], h1[8];
#pragma unroll
      for (int j = 0; j < 8; ++j) {
        h0[j] = b0p[j] + xa[0] * w0p[j] + xa[1] * w0p[8 + j] + xa[2] * w0p[16 + j];
        h1[j] = b0p[j] + xb[0] * w0p[j] + xb[1] * w0p[8 + j] + xb[2] * w0p[16 + j];
      }
      ln_leaky<8>(h0, g0p, be0p, ya);
      ln_leaky<8>(h1, g0p, be0p, yb);
    }
    {
      float h0[8], h1[8];
#pragma unroll
      for (int j = 0; j < 8; ++j) { h0[j] = b1p[j]; h1[j] = b1p[j]; }
#pragma unroll
      for (int i = 0; i < 8; ++i) {
#pragma unroll
        for (int j = 0; j < 8; ++j) {
          float w = w1p[i * 8 + j];
          h0[j] += ya[i] * w; h1[j] += yb[i] * w;
        }
      }
      ln_leaky<8>(h0, g1p, be1p, ya);
      ln_leaky<8>(h1, g1p, be1p, yb);
    }
    {
      float h0[16], h1[16];
#pragma unroll
      for (int j = 0; j < 16; ++j) { h0[j] = b2p[j]; h1[j] = b2p[j]; }
#pragma unroll
      for (int i = 0; i < 8; ++i) {
#pragma unroll
        for (int j = 0; j < 16; ++j) {
          float w = w2p[i * 16 + j];
          h0[j] += ya[i] * w; h1[j] += yb[i] * w;
        }
      }
      float z0[16], z1[16];
      ln_leaky<16>(h0, g2p, be2p, z0);
      ln_leaky<16>(h1, g2p, be2p, z1);
      // w_sT[s][m*16+k]: pack both k's (wk, wk+1) into one b32 per m
      bf16* wp = w_sT + ws * 264 + wk;
#pragma unroll
      for (int m = 0; m < 16; ++m)
        *(unsigned*)(wp + m * 16) = pack2(z0[m], z1[m]);
    }
  }

  // ---- MFMA wave geometry ----
  const int lane = tid & 63;
  const int wv = tid >> 6;
  const int l16 = lane & 15;
  const int q = lane >> 4;
  // agg-MFMA lane roles
  const bool adiag = ((((lane >> 5) ^ (lane >> 3)) & 1) == 0);
  const int aoff = ((lane >> 3) & 1) * 144 + (lane & 7) * 16 + (q & 1) * 8;
  const int boff = (lane >> 5) * 264 + l16 * 16 + (q & 1) * 8;
  // packed agg C-write: dword offset within s-row (row stride 160 el = 80 dw)
  const int cdw = ((q & 1) << 5) + l16;
  f32x4 a00 = {0.f, 0.f, 0.f, 0.f};
  f32x4 a01 = a00, a10 = a00, a11 = a00;
  const f32x4 zc = a00;

  const bf16* ptB = ptT + (size_t)b * N_ * 64;

  uint4 pf0, pf1;
  pf0 = *(const uint4*)(ptB + (size_t)iw0 * 64);
  pf1 = *(const uint4*)(ptB + (size_t)iw1 * 64);

  for (int ch = 0; ch < 9; ++ch) {
    const int nkk = (ch < 8) ? 4 : 2;
    __syncthreads();  // (A) prev agg done with feat2/w_sT reads; prev main done with aggA
    // stage feat2[s][c*16+k]: paired-k b32 writes (8 per thread)
    if (ch < 8) {
      const unsigned* a4 = (const unsigned*)&pf0;
      const unsigned* b4 = (const unsigned*)&pf1;
      unsigned* fb = (unsigned*)(feat2 + ws * 144 + wk);  // even element -> aligned
#pragma unroll
      for (int w = 0; w < 4; ++w) {
        unsigned a = a4[w], bb = b4[w];
        fb[(2 * w) * 8] = (a & 0xffffu) | (bb << 16);          // channel 2w
        fb[(2 * w + 1) * 8] = (a >> 16) | (bb & 0xffff0000u);  // channel 2w+1
      }
    } else {
      // gxn channels (3 real + 5 zero), packed pairs (wk, wk+1)
      bf16* fp = feat2 + ws * 144 + wk;
      *(unsigned*)(fp + 0 * 16) = pack2(xa[0], xb[0]);
      *(unsigned*)(fp + 1 * 16) = pack2(xa[1], xb[1]);
      *(unsigned*)(fp + 2 * 16) = pack2(xa[2], xb[2]);
#pragma unroll
      for (int c = 3; c < 8; ++c) *(unsigned*)(fp + c * 16) = 0u;
    }
    __syncthreads();  // (B)
    if (ch < 7) {  // prefetch next chunk's gather
      pf0 = *(const uint4*)(ptB + (size_t)iw0 * 64 + (ch + 1) * 8);
      pf1 = *(const uint4*)(ptB + (size_t)iw1 * 64 + (ch + 1) * 8);
    }
    // agg via block-diagonal MFMA: 2 s per MFMA, 4 MFMAs per wave.
    // C-write packed: granule kk holds channels {2kk, 2kk+1} at position m*2+cl2;
    // lane's 4 values are (c = (q&1)*4 + r, m = l16) -> two b32 writes.
#pragma unroll
    for (int pp = 0; pp < 4; ++pp) {
      int s2 = (wv * 4 + pp) * 2;
      uint4 au = *(const uint4*)(feat2 + s2 * 144 + aoff);
      if (!adiag) au = make_uint4(0u, 0u, 0u, 0u);
      bf16x8 af = __builtin_bit_cast(bf16x8, au);
      bf16x8 bw = *(const bf16x8*)(w_sT + s2 * 264 + boff);
      f32x4 d = __builtin_amdgcn_mfma_f32_16x16x32_bf16(af, bw, zc, 0, 0, 0);
      unsigned* cw = (unsigned*)(aggA + (size_t)(s2 + (lane >> 5)) * 160);
      cw[cdw] = pack2(d[0], d[1]);
      cw[cdw + 16] = pack2(d[2], d[3]);
    }
    __syncthreads();  // (C)
    // main GEMM: A from aggA (LDS), B from wlF (global, coalesced 1KB/wave).
    // Wave wv: rows 0..31 (both row-tiles), col tiles {wv, wv+4}.
    {
      const bf16* arow0 = aggA + l16 * 160 + q * 8;
      const bf16* arow1 = aggA + (16 + l16) * 160 + q * 8;
      const size_t lb = (size_t)lane * 8;
      const size_t kb = (size_t)(ch * 4) * 512;
      const bf16* w0f = wlF + (size_t)wv * 17408 + kb + lb;
      const bf16* w1f = wlF + (size_t)(wv + 4) * 17408 + kb + lb;
      for (int kk = 0; kk < nkk; ++kk) {
        bf16x8 af0 = *(const bf16x8*)(arow0 + kk * 32);
        bf16x8 af1 = *(const bf16x8*)(arow1 + kk * 32);
        bf16x8 bf0 = *(const bf16x8*)(w0f + kk * 512);
        bf16x8 bf1 = *(const bf16x8*)(w1f + kk * 512);
        a00 = __builtin_amdgcn_mfma_f32_16x16x32_bf16(af0, bf0, a00, 0, 0, 0);
        a01 = __builtin_amdgcn_mfma_f32_16x16x32_bf16(af0, bf1, a01, 0, 0, 0);
        a10 = __builtin_amdgcn_mfma_f32_16x16x32_bf16(af1, bf0, a10, 0, 0, 0);
        a11 = __builtin_amdgcn_mfma_f32_16x16x32_bf16(af1, bf1, a11, 0, 0, 0);
      }
    }
  }

  __syncthreads();
  // ---- epilogue: +bl, LN(128), *gl+bel, leaky, transposed f32 store ----
  float* out_s = (float*)w_sT;  // [32][132]; w_sT dead now
  {
    // a00: rows q*4+r, col wv*16+l16;  a01: +64 col;  a10/a11: rows +16.
    int row0 = q * 4;
    int row1 = 16 + q * 4;
    int c0 = wv * 16 + l16;
    int c1 = 64 + c0;
    float bl0 = blp[c0], bl1 = blp[c1];
#pragma unroll
    for (int r = 0; r < 4; ++r) {
      out_s[(row0 + r) * 132 + c0] = a00[r] + bl0;
      out_s[(row0 + r) * 132 + c1] = a01[r] + bl1;
      out_s[(row1 + r) * 132 + c0] = a10[r] + bl0;
      out_s[(row1 + r) * 132 + c1] = a11[r] + bl1;
    }
  }
  __syncthreads();
  {
    int r = tid >> 3, g = tid & 7;
    const float* rowp = out_s + r * 132;
    float s1 = 0.f;
#pragma unroll
    for (int i = 0; i < 16; ++i) s1 += rowp[g + 8 * i];
    s1 += __shfl_xor(s1, 1);
    s1 += __shfl_xor(s1, 2);
    s1 += __shfl_xor(s1, 4);
    float m = s1 * (1.0f / 128.0f);
    float s2 = 0.f;
#pragma unroll
    for (int i = 0; i < 16; ++i) { float d = rowp[g + 8 * i] - m; s2 += d * d; }
    s2 += __shfl_xor(s2, 1);
    s2 += __shfl_xor(s2, 2);
    s2 += __shfl_xor(s2, 4);
    if (g == 0) {
      ln_m[r] = m;
      ln_i[r] = rsqrtf(s2 * (1.0f / 128.0f) + 1e-5f);
    }
  }
  __syncthreads();
  {
    int d = tid >> 1, sh = tid & 1;
    float gld = glp[d], beld = belp[d];
    float vals[16];
#pragma unroll
    for (int j = 0; j < 16; ++j) {
      int r = sh * 16 + j;
      float v = (out_s[r * 132 + d] - ln_m[r]) * ln_i[r] * gld + beld;
      vals[j] = v < 0.f ? 0.2f * v : v;
    }
    float* op = out + ((size_t)b * DOUT + d) * S_ + s0 + sh * 16;
#pragma unroll
    for (int i = 0; i < 4; ++i)
      *(float4*)(op + 4 * i) =
          make_float4(vals[4 * i], vals[4 * i + 1], vals[4 * i + 2], vals[4 * i + 3]);
  }
}

extern "C" void kernel_launch(void* const* d_in, const int* in_sizes, int n_in,
                              void* d_out, int out_size, void* d_ws, size_t ws_size,
                              hipStream_t stream) {
  const float* xyz  = (const float*)d_in[0];
  const float* pts  = (const float*)d_in[1];
  const float* nxyz = (const float*)d_in[2];
  const int* nnidx  = (const int*)d_in[3];
  const float* w0p  = (const float*)d_in[4];
  const float* b0p  = (const float*)d_in[5];
  const float* g0p  = (const float*)d_in[6];
  const float* be0p = (const float*)d_in[7];
  const float* w1p  = (const float*)d_in[8];
  const float* b1p  = (const float*)d_in[9];
  const float* g1p  = (const float*)d_in[10];
  const float* be1p = (const float*)d_in[11];
  const float* w2p  = (const float*)d_in[12];
  const float* b2p  = (const float*)d_in[13];
  const float* g2p  = (const float*)d_in[14];
  const float* be2p = (const float*)d_in[15];
  const float* wlp  = (const float*)d_in[16];
  const float* blp  = (const float*)d_in[17];
  const float* glp  = (const float*)d_in[18];
  const float* belp = (const float*)d_in[19];
  float* out = (float*)d_out;

  const size_t PTT_BYTES = (size_t)B_ * N_ * 64 * 2;       // 33.55 MB
  const size_t WLF_BYTES = (size_t)8 * 34 * 64 * 8 * 2;    // 0.27 MB
  bf16* ptT = (bf16*)d_ws;
  bf16* wlF = (bf16*)((char*)d_ws + PTT_BYTES);

  (void)hipGetLastError();

  if (ws_size < PTT_BYTES + WLF_BYTES) {
    k_fill<<<dim3(8), dim3(256), 0, stream>>>(out, 5000.0f);
    return;
  }

  k_prep<<<dim3(1024 + 8 * 34), dim3(256), 0, stream>>>(pts, ptT, wlp, wlF);
  hipError_t e1 = hipGetLastError();
  k_main<<<dim3(S_ / TS, B_), dim3(256), 0, stream>>>(
      xyz, nxyz, nnidx, ptT, wlF,
      w0p, b0p, g0p, be0p, w1p, b1p, g1p, be1p,
      w2p, b2p, g2p, be2p, blp, glp, belp, out);
  hipError_t e3 = hipGetLastError();

  if (e1 != hipSuccess)
    k_fill<<<dim3(8), dim3(256), 0, stream>>>(out, 2000.0f + (float)(int)e1);
  if (e3 != hipSuccess)
    k_fill<<<dim3(8), dim3(256), 0, stream>>>(out, 4000.0f + (float)(int)e3);
}

// Round 10
// 227.343 us; speedup vs baseline: 1.0708x; 1.0198x over previous
//
#include <hip/hip_runtime.h>

#define B_ 16
#define N_ 16384
#define S_ 4096
#define K_ 16
#define TS 32
#define DOUT 128

typedef __bf16 bf16;
typedef __attribute__((ext_vector_type(8))) __bf16 bf16x8;
typedef __attribute__((ext_vector_type(4))) float f32x4;

__device__ __forceinline__ unsigned pack2(float a, float b) {
  unsigned short ua = __builtin_bit_cast(unsigned short, (bf16)a);
  unsigned short ub = __builtin_bit_cast(unsigned short, (bf16)b);
  return (unsigned)ua | ((unsigned)ub << 16);
}

template <int NCH>
__device__ __forceinline__ void ln_leaky(const float* h, const float* g, const float* e, float* o) {
  float m = 0.f;
#pragma unroll
  for (int j = 0; j < NCH; ++j) m += h[j];
  m *= (1.0f / NCH);
  float v = 0.f;
#pragma unroll
  for (int j = 0; j < NCH; ++j) { float d = h[j] - m; v += d * d; }
  v *= (1.0f / NCH);
  float inv = rsqrtf(v + 1e-5f);
#pragma unroll
  for (int j = 0; j < NCH; ++j) {
    float t = (h[j] - m) * inv * g[j] + e[j];
    o[j] = t < 0.f ? 0.2f * t : t;
  }
}

__global__ void k_fill(float* out, float v) {
  out[blockIdx.x * 256 + threadIdx.x] = v;
}

// Fused prep: blocks [0,1024) transpose points [B,64,N] f32 -> ptT [B,N,64] bf16
// with XCD-affine batch mapping; blocks [1024,1296) build wlF.
// wlF k-order within each 32-wide granule is m-major: position p = m*2 + cl2,
// channel c = kkg*2 + cl2 (matches the packed aggA write layout in k_main).
__global__ __launch_bounds__(256) void k_prep(const float* __restrict__ pts,
                                              bf16* __restrict__ pt,
                                              const float* __restrict__ wl,
                                              bf16* __restrict__ wlF) {
  int bi = blockIdx.x;
  if (bi < 1024) {
    int xcd = bi & 7;
    int li = bi >> 3;                  // 0..127
    int b = xcd * 2 + (li >> 6);       // batch: XCD x -> {2x, 2x+1}
    int n0 = (li & 63) * 256;
    int tc = threadIdx.x & 7;
    int tn = threadIdx.x >> 3;
    const float* src = pts + (size_t)b * 64 * N_ + (size_t)(tc * 8) * N_ + n0 + tn * 8;
    float4 row[8][2];
#pragma unroll
    for (int i = 0; i < 8; ++i) {
      row[i][0] = *(const float4*)(src + (size_t)i * N_);
      row[i][1] = *(const float4*)(src + (size_t)i * N_ + 4);
    }
    bf16* dst = pt + ((size_t)b * N_ + n0 + tn * 8) * 64 + tc * 8;
#pragma unroll
    for (int j = 0; j < 8; ++j) {
      float v[8];
#pragma unroll
      for (int i = 0; i < 8; ++i) {
        float4 q = row[i][j >> 2];
        v[i] = ((j & 3) == 0) ? q.x : ((j & 3) == 1) ? q.y : ((j & 3) == 2) ? q.z : q.w;
      }
      *(uint4*)(dst + (size_t)j * 64) = make_uint4(
          pack2(v[0], v[1]), pack2(v[2], v[3]), pack2(v[4], v[5]), pack2(v[6], v[7]));
    }
  } else {
    int blk = bi - 1024;               // t*34 + kkg
    int kkg = blk % 34;
    int t = blk / 34;
    int tid = threadIdx.x;
    int L = tid >> 2, jp = (tid & 3) * 2;
    int p0 = ((L >> 4) << 3) + jp;     // even position within 32-granule
    int m = p0 >> 1;
    int c0 = kkg * 2;                  // cl2 = 0
    int c1 = c0 + 1;                   // cl2 = 1
    int n = t * 16 + (L & 15);
    float v0 = (c0 < 67) ? wl[(size_t)(c0 * 16 + m) * 128 + n] : 0.f;
    float v1 = (c1 < 67) ? wl[(size_t)(c1 * 16 + m) * 128 + n] : 0.f;
    ((unsigned*)wlF)[(size_t)blk * 256 + tid] = pack2(v0, v1);
  }
}

// Barrier-minimal loop: feat2 and w_sT are WAVE-LOCAL (wave wv writes and reads
// exactly rows [wv*8, wv*8+8) of each; DS pipe is in-order per wave), so no
// barrier is needed between stage/WeightNet writes and agg reads. Only aggA is
// cross-wave (agg writes wv's rows, main reads all 32) -> 2 barriers/chunk:
//   { stage ; prefetch ; agg } -> sync -> main -> sync
__global__ __launch_bounds__(256, 4) void k_main(
    const float* __restrict__ xyz, const float* __restrict__ nxyz,
    const int* __restrict__ nnidx,
    const bf16* __restrict__ ptT, const bf16* __restrict__ wlF,
    const float* __restrict__ w0p, const float* __restrict__ b0p,
    const float* __restrict__ g0p, const float* __restrict__ be0p,
    const float* __restrict__ w1p, const float* __restrict__ b1p,
    const float* __restrict__ g1p, const float* __restrict__ be1p,
    const float* __restrict__ w2p, const float* __restrict__ b2p,
    const float* __restrict__ g2p, const float* __restrict__ be2p,
    const float* __restrict__ blp, const float* __restrict__ glp,
    const float* __restrict__ belp, float* __restrict__ out) {
  // LDS (37.4 KB total -> 4 blocks/CU):
  __shared__ __align__(16) bf16 w_sT[32 * 264];   // [s][m*16+k], s-stride 264 (pad 8)
  __shared__ __align__(16) bf16 feat2[32 * 144];  // [s][c*16+k], s-stride 144 (pad 16)
  __shared__ __align__(16) bf16 aggA[32 * 160];   // [s][granule-packed], s-stride 160
  __shared__ float nx[3][TS];
  __shared__ float ln_m[TS], ln_i[TS];

  const int tid = threadIdx.x;
  // XCD-affinity: XCD x owns batches {2x, 2x+1} (bijective remap).
  const unsigned Lwg = blockIdx.y * 128u + blockIdx.x;
  const int xcd = (int)(Lwg & 7u);
  const int li = (int)(Lwg >> 3);          // 0..255 within XCD
  const int b = xcd * 2 + (li >> 7);       // batch
  const int s0 = (li & 127) * TS;          // s-tile origin
  const size_t ibase = ((size_t)b * S_ + s0) * K_;

  if (tid < 96) {
    int c = tid >> 5, j = tid & 31;
    nx[c][j] = nxyz[((size_t)b * 3 + c) * S_ + s0 + j];
  }
  // ONE index pair per thread: points (s = tid>>3, k = 2*(tid&7)) and +1.
  // Serves both WeightNet and the gather staging (paired-k b32 writes).
  const int iw0 = nnidx[ibase + 2 * tid];
  const int iw1 = nnidx[ibase + 2 * tid + 1];
  __syncthreads();  // nx ready (cross-wave)

  // ---- WeightNet: points (ws, wk) and (ws, wk+1) ----
  float xa[3], xb[3];
  const int ws = tid >> 3;        // s
  const int wk = (tid & 7) * 2;   // even k
  {
#pragma unroll
    for (int c = 0; c < 3; ++c) {
      float nv = nx[c][ws];
      xa[c] = xyz[((size_t)b * 3 + c) * N_ + iw0] - nv;
      xb[c] = xyz[((size_t)b * 3 + c) * N_ + iw1] - nv;
    }
    float ya[8], yb[8];
    {
      float h0[8], h1[8];
#pragma unroll
      for (int j = 0; j < 8; ++j) {
        h0[j] = b0p[j] + xa[0] * w0p[j] + xa[1] * w0p[8 + j] + xa[2] * w0p[16 + j];
        h1[j] = b0p[j] + xb[0] * w0p[j] + xb[1] * w0p[8 + j] + xb[2] * w0p[16 + j];
      }
      ln_leaky<8>(h0, g0p, be0p, ya);
      ln_leaky<8>(h1, g0p, be0p, yb);
    }
    {
      float h0[8], h1[8];
#pragma unroll
      for (int j = 0; j < 8; ++j) { h0[j] = b1p[j]; h1[j] = b1p[j]; }
#pragma unroll
      for (int i = 0; i < 8; ++i) {
#pragma unroll
        for (int j = 0; j < 8; ++j) {
          float w = w1p[i * 8 + j];
          h0[j] += ya[i] * w; h1[j] += yb[i] * w;
        }
      }
      ln_leaky<8>(h0, g1p, be1p, ya);
      ln_leaky<8>(h1, g1p, be1p, yb);
    }
    {
      float h0[16], h1[16];
#pragma unroll
      for (int j = 0; j < 16; ++j) { h0[j] = b2p[j]; h1[j] = b2p[j]; }
#pragma unroll
      for (int i = 0; i < 8; ++i) {
#pragma unroll
        for (int j = 0; j < 16; ++j) {
          float w = w2p[i * 16 + j];
          h0[j] += ya[i] * w; h1[j] += yb[i] * w;
        }
      }
      float z0[16], z1[16];
      ln_leaky<16>(h0, g2p, be2p, z0);
      ln_leaky<16>(h1, g2p, be2p, z1);
      // w_sT[s][m*16+k]: pack both k's (wk, wk+1) into one b32 per m.
      // Wave-local: rows [wv*8, wv*8+8) — read back only by this wave's agg.
      bf16* wp = w_sT + ws * 264 + wk;
#pragma unroll
      for (int m = 0; m < 16; ++m)
        *(unsigned*)(wp + m * 16) = pack2(z0[m], z1[m]);
    }
  }

  // ---- MFMA wave geometry ----
  const int lane = tid & 63;
  const int wv = tid >> 6;
  const int l16 = lane & 15;
  const int q = lane >> 4;
  // agg-MFMA lane roles
  const bool adiag = ((((lane >> 5) ^ (lane >> 3)) & 1) == 0);
  const int aoff = ((lane >> 3) & 1) * 144 + (lane & 7) * 16 + (q & 1) * 8;
  const int boff = (lane >> 5) * 264 + l16 * 16 + (q & 1) * 8;
  // packed agg C-write: dword offset within s-row (row stride 160 el = 80 dw)
  const int cdw = ((q & 1) << 5) + l16;
  f32x4 a00 = {0.f, 0.f, 0.f, 0.f};
  f32x4 a01 = a00, a10 = a00, a11 = a00;
  const f32x4 zc = a00;

  const bf16* ptB = ptT + (size_t)b * N_ * 64;

  uint4 pf0, pf1;
  pf0 = *(const uint4*)(ptB + (size_t)iw0 * 64);
  pf1 = *(const uint4*)(ptB + (size_t)iw1 * 64);

  for (int ch = 0; ch < 9; ++ch) {
    const int nkk = (ch < 8) ? 4 : 2;
    // stage feat2[s][c*16+k]: paired-k b32 writes (8 per thread). Wave-local
    // (rows [wv*8,+8)); consumed by this wave's agg below — no barrier needed.
    if (ch < 8) {
      const unsigned* a4 = (const unsigned*)&pf0;
      const unsigned* b4 = (const unsigned*)&pf1;
      unsigned* fb = (unsigned*)(feat2 + ws * 144 + wk);  // even element -> aligned
#pragma unroll
      for (int w = 0; w < 4; ++w) {
        unsigned a = a4[w], bb = b4[w];
        fb[(2 * w) * 8] = (a & 0xffffu) | (bb << 16);          // channel 2w
        fb[(2 * w + 1) * 8] = (a >> 16) | (bb & 0xffff0000u);  // channel 2w+1
      }
    } else {
      // gxn channels (3 real + 5 zero), packed pairs (wk, wk+1)
      bf16* fp = feat2 + ws * 144 + wk;
      *(unsigned*)(fp + 0 * 16) = pack2(xa[0], xb[0]);
      *(unsigned*)(fp + 1 * 16) = pack2(xa[1], xb[1]);
      *(unsigned*)(fp + 2 * 16) = pack2(xa[2], xb[2]);
#pragma unroll
      for (int c = 3; c < 8; ++c) *(unsigned*)(fp + c * 16) = 0u;
    }
    if (ch < 7) {  // prefetch next chunk's gather (consumed at stage of ch+1)
      pf0 = *(const uint4*)(ptB + (size_t)iw0 * 64 + (ch + 1) * 8);
      pf1 = *(const uint4*)(ptB + (size_t)iw1 * 64 + (ch + 1) * 8);
    }
    // agg via block-diagonal MFMA: 2 s per MFMA, 4 MFMAs per wave.
    // Reads feat2/w_sT rows [wv*8,+8) (same-wave, in-order DS); writes aggA
    // rows [wv*8,+8) (packed: granule kk holds channels {2kk,2kk+1} at
    // position m*2+cl2) -> two b32 writes per lane.
#pragma unroll
    for (int pp = 0; pp < 4; ++pp) {
      int s2 = (wv * 4 + pp) * 2;
      uint4 au = *(const uint4*)(feat2 + s2 * 144 + aoff);
      if (!adiag) au = make_uint4(0u, 0u, 0u, 0u);
      bf16x8 af = __builtin_bit_cast(bf16x8, au);
      bf16x8 bw = *(const bf16x8*)(w_sT + s2 * 264 + boff);
      f32x4 d = __builtin_amdgcn_mfma_f32_16x16x32_bf16(af, bw, zc, 0, 0, 0);
      unsigned* cw = (unsigned*)(aggA + (size_t)(s2 + (lane >> 5)) * 160);
      cw[cdw] = pack2(d[0], d[1]);
      cw[cdw + 16] = pack2(d[2], d[3]);
    }
    __syncthreads();  // (C) aggA ready for cross-wave main reads
    // main GEMM: A from aggA (LDS, all 32 rows), B from wlF (global, coalesced).
    // Wave wv: rows 0..31 (both row-tiles), col tiles {wv, wv+4}.
    {
      const bf16* arow0 = aggA + l16 * 160 + q * 8;
      const bf16* arow1 = aggA + (16 + l16) * 160 + q * 8;
      const size_t lb = (size_t)lane * 8;
      const size_t kb = (size_t)(ch * 4) * 512;
      const bf16* w0f = wlF + (size_t)wv * 17408 + kb + lb;
      const bf16* w1f = wlF + (size_t)(wv + 4) * 17408 + kb + lb;
      for (int kk = 0; kk < nkk; ++kk) {
        bf16x8 af0 = *(const bf16x8*)(arow0 + kk * 32);
        bf16x8 af1 = *(const bf16x8*)(arow1 + kk * 32);
        bf16x8 bf0 = *(const bf16x8*)(w0f + kk * 512);
        bf16x8 bf1 = *(const bf16x8*)(w1f + kk * 512);
        a00 = __builtin_amdgcn_mfma_f32_16x16x32_bf16(af0, bf0, a00, 0, 0, 0);
        a01 = __builtin_amdgcn_mfma_f32_16x16x32_bf16(af0, bf1, a01, 0, 0, 0);
        a10 = __builtin_amdgcn_mfma_f32_16x16x32_bf16(af1, bf0, a10, 0, 0, 0);
        a11 = __builtin_amdgcn_mfma_f32_16x16x32_bf16(af1, bf1, a11, 0, 0, 0);
      }
    }
    __syncthreads();  // (A) main done; aggA free for next chunk's agg
  }

  // ---- epilogue: +bl, LN(128), *gl+bel, leaky, transposed f32 store ----
  // out_s aliases w_sT; last cross-wave-relevant w_sT read was agg(8), which
  // is separated from here by barriers (C) and (A) of ch=8.
  float* out_s = (float*)w_sT;  // [32][132]
  {
    // a00: rows q*4+r, col wv*16+l16;  a01: +64 col;  a10/a11: rows +16.
    int row0 = q * 4;
    int row1 = 16 + q * 4;
    int c0 = wv * 16 + l16;
    int c1 = 64 + c0;
    float bl0 = blp[c0], bl1 = blp[c1];
#pragma unroll
    for (int r = 0; r < 4; ++r) {
      out_s[(row0 + r) * 132 + c0] = a00[r] + bl0;
      out_s[(row0 + r) * 132 + c1] = a01[r] + bl1;
      out_s[(row1 + r) * 132 + c0] = a10[r] + bl0;
      out_s[(row1 + r) * 132 + c1] = a11[r] + bl1;
    }
  }
  __syncthreads();
  {
    int r = tid >> 3, g = tid & 7;
    const float* rowp = out_s + r * 132;
    float s1 = 0.f;
#pragma unroll
    for (int i = 0; i < 16; ++i) s1 += rowp[g + 8 * i];
    s1 += __shfl_xor(s1, 1);
    s1 += __shfl_xor(s1, 2);
    s1 += __shfl_xor(s1, 4);
    float m = s1 * (1.0f / 128.0f);
    float s2 = 0.f;
#pragma unroll
    for (int i = 0; i < 16; ++i) { float d = rowp[g + 8 * i] - m; s2 += d * d; }
    s2 += __shfl_xor(s2, 1);
    s2 += __shfl_xor(s2, 2);
    s2 += __shfl_xor(s2, 4);
    if (g == 0) {
      ln_m[r] = m;
      ln_i[r] = rsqrtf(s2 * (1.0f / 128.0f) + 1e-5f);
    }
  }
  __syncthreads();
  {
    int d = tid >> 1, sh = tid & 1;
    float gld = glp[d], beld = belp[d];
    float vals[16];
#pragma unroll
    for (int j = 0; j < 16; ++j) {
      int r = sh * 16 + j;
      float v = (out_s[r * 132 + d] - ln_m[r]) * ln_i[r] * gld + beld;
      vals[j] = v < 0.f ? 0.2f * v : v;
    }
    float* op = out + ((size_t)b * DOUT + d) * S_ + s0 + sh * 16;
#pragma unroll
    for (int i = 0; i < 4; ++i)
      *(float4*)(op + 4 * i) =
          make_float4(vals[4 * i], vals[4 * i + 1], vals[4 * i + 2], vals[4 * i + 3]);
  }
}

extern "C" void kernel_launch(void* const* d_in, const int* in_sizes, int n_in,
                              void* d_out, int out_size, void* d_ws, size_t ws_size,
                              hipStream_t stream) {
  const float* xyz  = (const float*)d_in[0];
  const float* pts  = (const float*)d_in[1];
  const float* nxyz = (const float*)d_in[2];
  const int* nnidx  = (const int*)d_in[3];
  const float* w0p  = (const float*)d_in[4];
  const float* b0p  = (const float*)d_in[5];
  const float* g0p  = (const float*)d_in[6];
  const float* be0p = (const float*)d_in[7];
  const float* w1p  = (const float*)d_in[8];
  const float* b1p  = (const float*)d_in[9];
  const float* g1p  = (const float*)d_in[10];
  const float* be1p = (const float*)d_in[11];
  const float* w2p  = (const float*)d_in[12];
  const float* b2p  = (const float*)d_in[13];
  const float* g2p  = (const float*)d_in[14];
  const float* be2p = (const float*)d_in[15];
  const float* wlp  = (const float*)d_in[16];
  const float* blp  = (const float*)d_in[17];
  const float* glp  = (const float*)d_in[18];
  const float* belp = (const float*)d_in[19];
  float* out = (float*)d_out;

  const size_t PTT_BYTES = (size_t)B_ * N_ * 64 * 2;       // 33.55 MB
  const size_t WLF_BYTES = (size_t)8 * 34 * 64 * 8 * 2;    // 0.27 MB
  bf16* ptT = (bf16*)d_ws;
  bf16* wlF = (bf16*)((char*)d_ws + PTT_BYTES);

  (void)hipGetLastError();

  if (ws_size < PTT_BYTES + WLF_BYTES) {
    k_fill<<<dim3(8), dim3(256), 0, stream>>>(out, 5000.0f);
    return;
  }

  k_prep<<<dim3(1024 + 8 * 34), dim3(256), 0, stream>>>(pts, ptT, wlp, wlF);
  hipError_t e1 = hipGetLastError();
  k_main<<<dim3(S_ / TS, B_), dim3(256), 0, stream>>>(
      xyz, nxyz, nnidx, ptT, wlF,
      w0p, b0p, g0p, be0p, w1p, b1p, g1p, be1p,
      w2p, b2p, g2p, be2p, blp, glp, belp, out);
  hipError_t e3 = hipGetLastError();

  if (e1 != hipSuccess)
    k_fill<<<dim3(8), dim3(256), 0, stream>>>(out, 2000.0f + (float)(int)e1);
  if (e3 != hipSuccess)
    k_fill<<<dim3(8), dim3(256), 0, stream>>>(out, 4000.0f + (float)(int)e3);
}